// Round 6
// baseline (277.450 us; speedup 1.0000x reference)
//
#include <hip/hip_runtime.h>

#define PIX 262144   // 512*512
#define CCH 64
#define KK  16
#define NSL 32       // slices
#define SLICE 8192   // PIX/NSL

// ws float layout (after packed/yv):
//   counts_s  [16][32]        (atomic-spread, memset to 0)
//   psum_part [16][64][32]    idx = (k*64+c)*32 + sl   (owned writes)
//   sumsq_part[16][64][32]    idx = (k*64+c)*32 + sl   (owned writes)
//   G_part    [16][64][32]    idx = (k*64+c)*32 + sl   (owned writes)

// ---------------- K1a: pack masks + spread-atomic counts ---------------------------
__global__ __launch_bounds__(256) void k1a_pack(
        const int* __restrict__ masks, unsigned short* __restrict__ packed,
        float* __restrict__ counts_s) {
    int t = blockIdx.x * 256 + threadIdx.x;   // 512 blocks * 256 thr * 2 px = PIX
    int p = t * 2;
    unsigned m0 = 0, m1 = 0;
    #pragma unroll
    for (int k = 0; k < KK; ++k) {
        int2 mv = *(const int2*)(masks + (size_t)k * PIX + p);
        m0 |= (unsigned)(mv.x == 1) << k;
        m1 |= (unsigned)(mv.y == 1) << k;
    }
    packed[p]     = (unsigned short)m0;
    packed[p + 1] = (unsigned short)m1;

    __shared__ float wc[4][16];
    int wid = threadIdx.x >> 6, lane = threadIdx.x & 63;
    #pragma unroll
    for (int k = 0; k < KK; ++k) {
        unsigned long long b0 = __ballot((m0 >> k) & 1u);
        unsigned long long b1 = __ballot((m1 >> k) & 1u);
        if (lane == 0) wc[wid][k] = (float)(__popcll(b0) + __popcll(b1));
    }
    __syncthreads();
    if (threadIdx.x < 16) {
        int k = threadIdx.x;
        float s = wc[0][k] + wc[1][k] + wc[2][k] + wc[3][k];
        atomicAdd(counts_s + k * 32 + (blockIdx.x & 31), s);
    }
}

// ---------------- K1b: y[p] = rsqrt(||X2col||^2), 4 px/thread, float4 --------------
__global__ __launch_bounds__(256) void k1b_ynorm(
        const float* __restrict__ x2, float* __restrict__ yv) {
    int p = (blockIdx.x * 256 + threadIdx.x) * 4;   // 256 blocks
    float4 s = make_float4(0.f, 0.f, 0.f, 0.f);
    #pragma unroll 16
    for (int c = 0; c < CCH; ++c) {
        float4 v = *(const float4*)(x2 + (size_t)c * PIX + p);
        s.x = fmaf(v.x, v.x, s.x);
        s.y = fmaf(v.y, v.y, s.y);
        s.z = fmaf(v.z, v.z, s.z);
        s.w = fmaf(v.w, v.w, s.w);
    }
    float4 y;
    y.x = (s.x > 0.f) ? rsqrtf(s.x) : 0.f;
    y.y = (s.y > 0.f) ? rsqrtf(s.y) : 0.f;
    y.z = (s.z > 0.f) ? rsqrtf(s.z) : 0.f;
    y.w = (s.w > 0.f) ? rsqrtf(s.w) : 0.f;
    *(float4*)(yv + p) = y;
}

__device__ __forceinline__ float wred64(float v) {
    #pragma unroll
    for (int o = 32; o > 0; o >>= 1) v += __shfl_xor(v, o, 64);
    return v;
}

// ---------------- K2: fused masked channel sums, ONE channel per block -------------
// blocks [0,2048):    type A — psum_part[k][c][sl] = sum M*X1, sumsq_part = sum M*X1^2
// blocks [2048,4096): type B — G_part[k][c][sl]    = sum M*y*X2
// Per-thread live set: acc[16] (+accQ[16] on A path) + few temps -> ~40-64 VGPR.
__global__ __launch_bounds__(256) void k2_fused(
        const float* __restrict__ x1, const float* __restrict__ x2,
        const unsigned short* __restrict__ packed, const float* __restrict__ yv,
        float* __restrict__ psum_part, float* __restrict__ sumsq_part,
        float* __restrict__ G_part) {
    int b = blockIdx.x;
    bool typeB = (b >= 2048);
    if (typeB) b -= 2048;
    int c  = b & 63;          // channel
    int sl = b >> 6;          // slice 0..31
    int base = sl * SLICE;
    int tid = threadIdx.x;

    const float* X = (typeB ? x2 : x1) + (size_t)c * PIX;

    float acc[16];
    float accQ[16];
    #pragma unroll
    for (int k = 0; k < 16; ++k) { acc[k] = 0.f; accQ[k] = 0.f; }

    for (int it = 0; it < 8; ++it) {
        int px = base + ((it << 8) + tid) * 4;
        float4 xv = *(const float4*)(X + px);
        ushort4 mv = *(const ushort4*)(packed + px);
        if (typeB) {
            float4 w = *(const float4*)(yv + px);
            xv.x *= w.x; xv.y *= w.y; xv.z *= w.z; xv.w *= w.w;
            float xs[4] = {xv.x, xv.y, xv.z, xv.w};
            unsigned ms[4] = {mv.x, mv.y, mv.z, mv.w};
            #pragma unroll
            for (int q = 0; q < 4; ++q) {
                unsigned m = ms[q];
                float xq = xs[q];
                #pragma unroll
                for (int k = 0; k < 16; ++k) {
                    float f = (float)((m >> k) & 1u);
                    acc[k] = fmaf(f, xq, acc[k]);
                }
            }
        } else {
            float xs[4] = {xv.x, xv.y, xv.z, xv.w};
            unsigned ms[4] = {mv.x, mv.y, mv.z, mv.w};
            #pragma unroll
            for (int q = 0; q < 4; ++q) {
                unsigned m = ms[q];
                float xq = xs[q];
                float x2q = xq * xq;
                #pragma unroll
                for (int k = 0; k < 16; ++k) {
                    float f = (float)((m >> k) & 1u);
                    acc[k]  = fmaf(f, xq,  acc[k]);
                    accQ[k] = fmaf(f, x2q, accQ[k]);
                }
            }
        }
    }

    __shared__ float red[16][4];
    __shared__ float redQ[16][4];
    int wid = tid >> 6, lane = tid & 63;
    #pragma unroll
    for (int k = 0; k < 16; ++k) {
        float v = wred64(acc[k]);
        if (lane == 0) red[k][wid] = v;
    }
    if (!typeB) {
        #pragma unroll
        for (int k = 0; k < 16; ++k) {
            float v = wred64(accQ[k]);
            if (lane == 0) redQ[k][wid] = v;
        }
    }
    __syncthreads();
    if (tid < 16) {
        float s = red[tid][0] + red[tid][1] + red[tid][2] + red[tid][3];
        int idx = (tid * 64 + c) * 32 + sl;
        if (typeB) {
            G_part[idx] = s;
        } else {
            psum_part[idx] = s;
            float sq = redQ[tid][0] + redQ[tid][1] + redQ[tid][2] + redQ[tid][3];
            sumsq_part[idx] = sq;
        }
    }
}

// ---------------- K3: reduce partials + finalize (fully parallel, LDS only) --------
__global__ __launch_bounds__(256) void k3_finalize(
        const int* __restrict__ labels, const float* __restrict__ counts_s,
        const float* __restrict__ psum_part, const float* __restrict__ sumsq_part,
        const float* __restrict__ G_part, float* __restrict__ out) {
    __shared__ float meansS[16][65];
    __shared__ float Gs[16][65];
    __shared__ float cntS[16], rawcS[16], nmS[16], stdS[16], rowS[16];
    __shared__ float ssq2[16][17];
    __shared__ float ssqS[16];
    __shared__ int   labS[16];
    __shared__ float simS[16][17];
    __shared__ float bred[4][6];
    int t = threadIdx.x;

    if (t < 16) {
        float s = 0.f;
        #pragma unroll 8
        for (int j = 0; j < 32; ++j) s += counts_s[t * 32 + j];
        rawcS[t] = s;
        cntS[t]  = fmaxf(s, 1.f);
        labS[t]  = labels[t];
    }
    // sumsq reduce: k = t>>4, seg = t&15 sums 128 contiguous floats (over c,sl)
    {
        int k = t >> 4, seg = t & 15;
        const float4* p4 = (const float4*)(sumsq_part + k * 2048 + seg * 128);
        float s = 0.f;
        #pragma unroll
        for (int j = 0; j < 32; ++j) {
            float4 v = p4[j];
            s += v.x + v.y + v.z + v.w;
        }
        ssq2[k][seg] = s;
    }
    __syncthreads();
    if (t < 16) {
        float s = 0.f;
        #pragma unroll
        for (int seg = 0; seg < 16; ++seg) s += ssq2[t][seg];
        ssqS[t] = s;
    }
    // psum/G slice reduce: i = (k,c), 32 contiguous slices each
    for (int i = t; i < 1024; i += 256) {
        int k = i >> 6, c = i & 63;
        const float4* pp = (const float4*)(psum_part + i * 32);
        const float4* pg = (const float4*)(G_part + i * 32);
        float sp = 0.f, sg = 0.f;
        #pragma unroll
        for (int j = 0; j < 8; ++j) {
            float4 a = pp[j], bq = pg[j];
            sp += a.x + a.y + a.z + a.w;
            sg += bq.x + bq.y + bq.z + bq.w;
        }
        meansS[k][c] = sp / cntS[k];
        Gs[k][c] = sg;
    }
    __syncthreads();
    if (t < 16) {
        float s2 = 0.f, sm = 0.f;
        for (int c = 0; c < 64; ++c) {
            float m = meansS[t][c];
            s2 = fmaf(m, m, s2);
            sm += m;
        }
        nmS[t] = sqrtf(s2);
        float ne = rawcS[t] * 64.f;
        float ma = (sm * cntS[t]) / fmaxf(ne, 1.f);   // == sum_all / max(n_elem,1)
        float var = (ssqS[t] - ne * ma * ma) / fmaxf(ne - 1.f, 1.f);
        stdS[t] = sqrtf(fmaxf(var, 0.f));
    }
    __syncthreads();
    {
        int i = t >> 4, j = t & 15;
        float d = 0.f;
        #pragma unroll 16
        for (int c = 0; c < 64; ++c) d = fmaf(meansS[i][c], Gs[j][c], d);
        simS[i][j] = d / (fmaxf(nmS[i], 1e-30f) * cntS[j]);
    }
    __syncthreads();
    if (t < 16) {
        float s = 0.f;
        int li = labS[t];
        for (int j = 0; j < 16; ++j)
            if (j != t && labS[j] == li) s += simS[t][j];
        rowS[t] = s;
    }
    // neg buckets: one pair per thread, block reduce
    float s0 = 0.f, s1 = 0.f, s2 = 0.f, c0 = 0.f, c1 = 0.f, c2 = 0.f;
    {
        int i = t >> 4, j = t & 15;
        int li = labS[i], lj = labS[j];
        if (li != lj) {
            float sv = simS[i][j];
            bool gi0 = li >= 1 && li <= 8,  gj0 = lj >= 1 && lj <= 8;
            bool gi1 = li >= 3 && li <= 10, gj1 = lj >= 3 && lj <= 10;
            bool gi2 = (li >= 1 && li <= 2) || (li >= 9 && li <= 10);
            bool gj2 = (lj >= 1 && lj <= 2) || (lj >= 9 && lj <= 10);
            if (gi0 && gj0) { s0 = sv; c0 = 1.f; }
            if (gi1 && gj1) { s1 = sv; c1 = 1.f; }
            if (gi2 && gj2) { s2 = sv; c2 = 1.f; }
        }
    }
    s0 = wred64(s0); s1 = wred64(s1); s2 = wred64(s2);
    c0 = wred64(c0); c1 = wred64(c1); c2 = wred64(c2);
    {
        int wid = t >> 6, lane = t & 63;
        if (lane == 0) {
            bred[wid][0] = s0; bred[wid][1] = s1; bred[wid][2] = s2;
            bred[wid][3] = c0; bred[wid][4] = c1; bred[wid][5] = c2;
        }
    }
    __syncthreads();
    if (t < 11) {
        float cc = 0.f, inst = 0.f, csim = 0.f, cstd = 0.f;
        for (int k = 0; k < 16; ++k) {
            if (labS[k] == t) {
                cc += 1.f;
                inst += simS[k][k];
                csim += rowS[k];
                cstd += stdS[k];
            }
        }
        if (cc > 1.f) {
            inst /= fmaxf(cc, 1.f);
            csim /= fmaxf(cc * (cc - 1.f), 1.f);
            cstd /= cc;
        }
        out[t]      = inst;
        out[11 + t] = csim;
        out[25 + t] = cstd;
    }
    if (t == 0) {
        float S0 = bred[0][0] + bred[1][0] + bred[2][0] + bred[3][0];
        float S1 = bred[0][1] + bred[1][1] + bred[2][1] + bred[3][1];
        float S2 = bred[0][2] + bred[1][2] + bred[2][2] + bred[3][2];
        float C0 = bred[0][3] + bred[1][3] + bred[2][3] + bred[3][3];
        float C1 = bred[0][4] + bred[1][4] + bred[2][4] + bred[3][4];
        float C2 = bred[0][5] + bred[1][5] + bred[2][5] + bred[3][5];
        out[22] = (C0 > 1.f) ? (S0 / C0) : S0;
        out[23] = (C1 > 1.f) ? (S1 / C1) : S1;
        out[24] = (C2 > 1.f) ? (S2 / C2) : S2;
    }
}

extern "C" void kernel_launch(void* const* d_in, const int* in_sizes, int n_in,
                              void* d_out, int out_size, void* d_ws, size_t ws_size,
                              hipStream_t stream) {
    const float* x1     = (const float*)d_in[0];
    const float* x2     = (const float*)d_in[1];
    const int*   masks  = (const int*)d_in[2];
    const int*   labels = (const int*)d_in[3];
    float* out = (float*)d_out;

    char* ws = (char*)d_ws;
    unsigned short* packed = (unsigned short*)ws;                    // 512 KB
    float* yv         = (float*)(ws + (size_t)PIX * 2);              // 1 MB
    float* counts_s   = (float*)(ws + (size_t)PIX * 6);              // 512 f
    float* psum_part  = counts_s + 512;                              // 32768 f
    float* sumsq_part = psum_part + 32768;                           // 32768 f
    float* G_part     = sumsq_part + 32768;                          // 32768 f

    hipMemsetAsync(counts_s, 0, 512 * sizeof(float), stream);
    k1a_pack<<<512, 256, 0, stream>>>(masks, packed, counts_s);
    k1b_ynorm<<<256, 256, 0, stream>>>(x2, yv);
    k2_fused<<<4096, 256, 0, stream>>>(x1, x2, packed, yv, psum_part, sumsq_part, G_part);
    k3_finalize<<<1, 256, 0, stream>>>(labels, counts_s, psum_part, sumsq_part, G_part, out);
}

// Round 7
// 202.559 us; speedup vs baseline: 1.3697x; 1.3697x over previous
//
#include <hip/hip_runtime.h>

#define PIX 262144   // 512*512
#define CCH 64
#define KK  16

typedef __attribute__((ext_vector_type(8))) short short8;
typedef __attribute__((ext_vector_type(4))) float f32x4;

__device__ __forceinline__ unsigned short f2bf(float f) {
    unsigned u = __float_as_uint(f);
    return (unsigned short)((u + 0x7FFFu + ((u >> 16) & 1u)) >> 16);
}
__device__ __forceinline__ float bf2f(unsigned short h) {
    return __uint_as_float(((unsigned)h) << 16);
}

// ---------------- K1a: pack masks + spread-atomic counts ---------------------------
__global__ __launch_bounds__(256) void k1a_pack(
        const int* __restrict__ masks, unsigned short* __restrict__ packed,
        float* __restrict__ counts_s) {
    int t = blockIdx.x * 256 + threadIdx.x;   // 512 blocks * 256 thr * 2 px = PIX
    int p = t * 2;
    unsigned m0 = 0, m1 = 0;
    #pragma unroll
    for (int k = 0; k < KK; ++k) {
        int2 mv = *(const int2*)(masks + (size_t)k * PIX + p);
        m0 |= (unsigned)(mv.x == 1) << k;
        m1 |= (unsigned)(mv.y == 1) << k;
    }
    packed[p]     = (unsigned short)m0;
    packed[p + 1] = (unsigned short)m1;

    __shared__ float wc[4][16];
    int wid = threadIdx.x >> 6, lane = threadIdx.x & 63;
    #pragma unroll
    for (int k = 0; k < KK; ++k) {
        unsigned long long b0 = __ballot((m0 >> k) & 1u);
        unsigned long long b1 = __ballot((m1 >> k) & 1u);
        if (lane == 0) wc[wid][k] = (float)(__popcll(b0) + __popcll(b1));
    }
    __syncthreads();
    if (threadIdx.x < 16) {
        int k = threadIdx.x;
        float s = wc[0][k] + wc[1][k] + wc[2][k] + wc[3][k];
        atomicAdd(counts_s + k * 32 + (blockIdx.x & 31), s);
    }
}

// ---------------- K1b: y[p] = rsqrt(||X2col||^2), 4 px/thread, float4 --------------
__global__ __launch_bounds__(256) void k1b_ynorm(
        const float* __restrict__ x2, float* __restrict__ yv) {
    int p = (blockIdx.x * 256 + threadIdx.x) * 4;   // 256 blocks
    float4 s = make_float4(0.f, 0.f, 0.f, 0.f);
    #pragma unroll 16
    for (int c = 0; c < CCH; ++c) {
        float4 v = *(const float4*)(x2 + (size_t)c * PIX + p);
        s.x = fmaf(v.x, v.x, s.x);
        s.y = fmaf(v.y, v.y, s.y);
        s.z = fmaf(v.z, v.z, s.z);
        s.w = fmaf(v.w, v.w, s.w);
    }
    float4 y;
    y.x = (s.x > 0.f) ? rsqrtf(s.x) : 0.f;
    y.y = (s.y > 0.f) ? rsqrtf(s.y) : 0.f;
    y.z = (s.z > 0.f) ? rsqrtf(s.z) : 0.f;
    y.w = (s.w > 0.f) ? rsqrtf(s.w) : 0.f;
    *(float4*)(yv + p) = y;
}

__device__ __forceinline__ float wred64(float v) {
    #pragma unroll
    for (int o = 32; o > 0; o >>= 1) v += __shfl_xor(v, o, 64);
    return v;
}

// ---------------- K2: MFMA masked GEMMs --------------------------------------------
// psum = M[16,P] @ X1^T[P,64]; psumsq = M @ (X1^2)^T; G = M @ (y*X2)^T.
// A-operand = mask (0/1 exact in bf16), B-operand = x as bf16 hi + lo (Dekker split),
// two MFMAs per quantity accumulate the exact fp32 value to ~2^-17 relative.
// Layouts (guide, m89/m120-verified): A[m=lane&15][k=quad*8+j];
// B[k=quad*8+j][n=lane&15]; D col=lane&15, row=quad*4+reg.
// blocks [0,512): A-pass (x1 -> psum,psumsq); [512,1024): B-pass (y*x2 -> G).
// Each block: 512 px (16 chunks of 32), wave w handles channels 16w..16w+15.
__global__ __launch_bounds__(256) void k2_mfma(
        const float* __restrict__ x1, const float* __restrict__ x2,
        const unsigned short* __restrict__ packed, const float* __restrict__ yv,
        float* __restrict__ psum_f, float* __restrict__ psumsq_f,
        float* __restrict__ G_f) {
    int b = blockIdx.x;
    bool typeB = (b >= 512);
    if (typeB) b -= 512;
    int lane = threadIdx.x & 63;
    int wv   = threadIdx.x >> 6;
    int quad = lane >> 4;
    int n    = lane & 15;          // = A row m = B col n = D col
    int ch   = wv * 16 + n;
    int base = b * 512;

    const float* Xrow = (typeB ? x2 : x1) + (size_t)ch * PIX;

    f32x4 acc0 = {0.f, 0.f, 0.f, 0.f};
    f32x4 acc1 = {0.f, 0.f, 0.f, 0.f};
    const short ONE = (short)0x3F80;   // bf16 1.0

    for (int cki = 0; cki < 16; ++cki) {
        int kof = base + cki * 32 + (quad << 3);   // this lane's 8-pixel k-range
        int4 pk = *(const int4*)(packed + kof);    // 8 ushort masks (16B aligned)
        float4 xa = *(const float4*)(Xrow + kof);
        float4 xb = *(const float4*)(Xrow + kof + 4);

        short8 af;
        af[0] = ((pk.x >> n) & 1)        ? ONE : (short)0;
        af[1] = ((pk.x >> (n + 16)) & 1) ? ONE : (short)0;
        af[2] = ((pk.y >> n) & 1)        ? ONE : (short)0;
        af[3] = ((pk.y >> (n + 16)) & 1) ? ONE : (short)0;
        af[4] = ((pk.z >> n) & 1)        ? ONE : (short)0;
        af[5] = ((pk.z >> (n + 16)) & 1) ? ONE : (short)0;
        af[6] = ((pk.w >> n) & 1)        ? ONE : (short)0;
        af[7] = ((pk.w >> (n + 16)) & 1) ? ONE : (short)0;

        float xs[8] = {xa.x, xa.y, xa.z, xa.w, xb.x, xb.y, xb.z, xb.w};
        if (typeB) {
            float4 ya = *(const float4*)(yv + kof);
            float4 yb = *(const float4*)(yv + kof + 4);
            float ys[8] = {ya.x, ya.y, ya.z, ya.w, yb.x, yb.y, yb.z, yb.w};
            #pragma unroll
            for (int j = 0; j < 8; ++j) xs[j] *= ys[j];
        }

        short8 bh, bl;
        #pragma unroll
        for (int j = 0; j < 8; ++j) {
            float v = xs[j];
            unsigned short h = f2bf(v);
            bh[j] = (short)h;
            bl[j] = (short)f2bf(v - bf2f(h));
        }
        acc0 = __builtin_amdgcn_mfma_f32_16x16x32_bf16(af, bh, acc0, 0, 0, 0);
        acc0 = __builtin_amdgcn_mfma_f32_16x16x32_bf16(af, bl, acc0, 0, 0, 0);

        if (!typeB) {
            short8 qh, ql;
            #pragma unroll
            for (int j = 0; j < 8; ++j) {
                float sq = xs[j] * xs[j];
                unsigned short h = f2bf(sq);
                qh[j] = (short)h;
                ql[j] = (short)f2bf(sq - bf2f(h));
            }
            acc1 = __builtin_amdgcn_mfma_f32_16x16x32_bf16(af, qh, acc1, 0, 0, 0);
            acc1 = __builtin_amdgcn_mfma_f32_16x16x32_bf16(af, ql, acc1, 0, 0, 0);
        }
    }

    int col = wv * 16 + n;
    #pragma unroll
    for (int r = 0; r < 4; ++r) {
        int row = quad * 4 + r;
        if (typeB) {
            atomicAdd(G_f + row * 64 + col, acc0[r]);
        } else {
            atomicAdd(psum_f + row * 64 + col, acc0[r]);
            atomicAdd(psumsq_f + row * 64 + col, acc1[r]);
        }
    }
}

// ---------------- K3: finalize (fully parallel, LDS only) --------------------------
__global__ __launch_bounds__(256) void k3_finalize(
        const int* __restrict__ labels, const float* __restrict__ counts_s,
        const float* __restrict__ psum_f, const float* __restrict__ psumsq_f,
        const float* __restrict__ G_f, float* __restrict__ out) {
    __shared__ float meansS[16][65];
    __shared__ float Gs[16][65];
    __shared__ float cntS[16], rawcS[16], nmS[16], stdS[16], rowS[16];
    __shared__ float ssq2[16][17];
    __shared__ float ssqS[16];
    __shared__ int   labS[16];
    __shared__ float simS[16][17];
    __shared__ float bred[4][6];
    int t = threadIdx.x;

    if (t < 16) {
        float s = 0.f;
        #pragma unroll 8
        for (int j = 0; j < 32; ++j) s += counts_s[t * 32 + j];
        rawcS[t] = s;
        cntS[t]  = fmaxf(s, 1.f);
        labS[t]  = labels[t];
    }
    // sumsq[k] = sum_c psumsq[k][c]: thread (k=t>>4, seg=t&15) sums 4 channels
    {
        int k = t >> 4, seg = t & 15;
        const float4 v = *(const float4*)(psumsq_f + k * 64 + seg * 4);
        ssq2[k][seg] = v.x + v.y + v.z + v.w;
    }
    __syncthreads();
    if (t < 16) {
        float s = 0.f;
        #pragma unroll
        for (int seg = 0; seg < 16; ++seg) s += ssq2[t][seg];
        ssqS[t] = s;
    }
    for (int i = t; i < 1024; i += 256) {
        int k = i >> 6, c = i & 63;
        meansS[k][c] = psum_f[i] / cntS[k];
        Gs[k][c] = G_f[i];
    }
    __syncthreads();
    if (t < 16) {
        float s2 = 0.f, sm = 0.f;
        for (int c = 0; c < 64; ++c) {
            float m = meansS[t][c];
            s2 = fmaf(m, m, s2);
            sm += m;
        }
        nmS[t] = sqrtf(s2);
        float ne = rawcS[t] * 64.f;
        float ma = (sm * cntS[t]) / fmaxf(ne, 1.f);   // == sum_all / max(n_elem,1)
        float var = (ssqS[t] - ne * ma * ma) / fmaxf(ne - 1.f, 1.f);
        stdS[t] = sqrtf(fmaxf(var, 0.f));
    }
    __syncthreads();
    {
        int i = t >> 4, j = t & 15;
        float d = 0.f;
        #pragma unroll 16
        for (int c = 0; c < 64; ++c) d = fmaf(meansS[i][c], Gs[j][c], d);
        simS[i][j] = d / (fmaxf(nmS[i], 1e-30f) * cntS[j]);
    }
    __syncthreads();
    if (t < 16) {
        float s = 0.f;
        int li = labS[t];
        for (int j = 0; j < 16; ++j)
            if (j != t && labS[j] == li) s += simS[t][j];
        rowS[t] = s;
    }
    // neg buckets: one pair per thread, block reduce
    float s0 = 0.f, s1 = 0.f, s2 = 0.f, c0 = 0.f, c1 = 0.f, c2 = 0.f;
    {
        int i = t >> 4, j = t & 15;
        int li = labS[i], lj = labS[j];
        if (li != lj) {
            float sv = simS[i][j];
            bool gi0 = li >= 1 && li <= 8,  gj0 = lj >= 1 && lj <= 8;
            bool gi1 = li >= 3 && li <= 10, gj1 = lj >= 3 && lj <= 10;
            bool gi2 = (li >= 1 && li <= 2) || (li >= 9 && li <= 10);
            bool gj2 = (lj >= 1 && lj <= 2) || (lj >= 9 && lj <= 10);
            if (gi0 && gj0) { s0 = sv; c0 = 1.f; }
            if (gi1 && gj1) { s1 = sv; c1 = 1.f; }
            if (gi2 && gj2) { s2 = sv; c2 = 1.f; }
        }
    }
    s0 = wred64(s0); s1 = wred64(s1); s2 = wred64(s2);
    c0 = wred64(c0); c1 = wred64(c1); c2 = wred64(c2);
    {
        int wid = t >> 6, lane = t & 63;
        if (lane == 0) {
            bred[wid][0] = s0; bred[wid][1] = s1; bred[wid][2] = s2;
            bred[wid][3] = c0; bred[wid][4] = c1; bred[wid][5] = c2;
        }
    }
    __syncthreads();
    if (t < 11) {
        float cc = 0.f, inst = 0.f, csim = 0.f, cstd = 0.f;
        for (int k = 0; k < 16; ++k) {
            if (labS[k] == t) {
                cc += 1.f;
                inst += simS[k][k];
                csim += rowS[k];
                cstd += stdS[k];
            }
        }
        if (cc > 1.f) {
            inst /= fmaxf(cc, 1.f);
            csim /= fmaxf(cc * (cc - 1.f), 1.f);
            cstd /= cc;
        }
        out[t]      = inst;
        out[11 + t] = csim;
        out[25 + t] = cstd;
    }
    if (t == 0) {
        float S0 = bred[0][0] + bred[1][0] + bred[2][0] + bred[3][0];
        float S1 = bred[0][1] + bred[1][1] + bred[2][1] + bred[3][1];
        float S2 = bred[0][2] + bred[1][2] + bred[2][2] + bred[3][2];
        float C0 = bred[0][3] + bred[1][3] + bred[2][3] + bred[3][3];
        float C1 = bred[0][4] + bred[1][4] + bred[2][4] + bred[3][4];
        float C2 = bred[0][5] + bred[1][5] + bred[2][5] + bred[3][5];
        out[22] = (C0 > 1.f) ? (S0 / C0) : S0;
        out[23] = (C1 > 1.f) ? (S1 / C1) : S1;
        out[24] = (C2 > 1.f) ? (S2 / C2) : S2;
    }
}

extern "C" void kernel_launch(void* const* d_in, const int* in_sizes, int n_in,
                              void* d_out, int out_size, void* d_ws, size_t ws_size,
                              hipStream_t stream) {
    const float* x1     = (const float*)d_in[0];
    const float* x2     = (const float*)d_in[1];
    const int*   masks  = (const int*)d_in[2];
    const int*   labels = (const int*)d_in[3];
    float* out = (float*)d_out;

    char* ws = (char*)d_ws;
    unsigned short* packed = (unsigned short*)ws;                    // 512 KB
    float* yv       = (float*)(ws + (size_t)PIX * 2);                // 1 MB
    float* counts_s = (float*)(ws + (size_t)PIX * 6);                // 512 f
    float* psum_f   = counts_s + 512;                                // 1024 f
    float* psumsq_f = psum_f + 1024;                                 // 1024 f
    float* G_f      = psumsq_f + 1024;                               // 1024 f

    hipMemsetAsync(counts_s, 0, (512 + 3 * 1024) * sizeof(float), stream);
    k1a_pack<<<512, 256, 0, stream>>>(masks, packed, counts_s);
    k1b_ynorm<<<256, 256, 0, stream>>>(x2, yv);
    k2_mfma<<<1024, 256, 0, stream>>>(x1, x2, packed, yv, psum_f, psumsq_f, G_f);
    k3_finalize<<<1, 256, 0, stream>>>(labels, counts_s, psum_f, psumsq_f, G_f, out);
}

// Round 8
// 201.980 us; speedup vs baseline: 1.3737x; 1.0029x over previous
//
#include <hip/hip_runtime.h>

#define PIX 262144   // 512*512
#define CCH 64
#define KK  16

typedef __attribute__((ext_vector_type(8))) short short8;
typedef __attribute__((ext_vector_type(4))) float f32x4;

// ---------------- K1: fused mask-pack(+counts) and y-norm --------------------------
// blocks [0,512): pack masks -> packed, counts via ballot (spread atomics)
// blocks [512,1024): y[p] = rsqrt(sum_c x2[c][p]^2)
__global__ __launch_bounds__(256) void k1_fused(
        const int* __restrict__ masks, const float* __restrict__ x2,
        unsigned short* __restrict__ packed, float* __restrict__ counts_s,
        float* __restrict__ yv) {
    __shared__ float wc[4][16];
    if (blockIdx.x < 512) {
        int t = blockIdx.x * 256 + threadIdx.x;
        int p = t * 2;
        unsigned m0 = 0, m1 = 0;
        #pragma unroll
        for (int k = 0; k < KK; ++k) {
            int2 mv = *(const int2*)(masks + (size_t)k * PIX + p);
            m0 |= (unsigned)(mv.x == 1) << k;
            m1 |= (unsigned)(mv.y == 1) << k;
        }
        packed[p]     = (unsigned short)m0;
        packed[p + 1] = (unsigned short)m1;

        int wid = threadIdx.x >> 6, lane = threadIdx.x & 63;
        #pragma unroll
        for (int k = 0; k < KK; ++k) {
            unsigned long long b0 = __ballot((m0 >> k) & 1u);
            unsigned long long b1 = __ballot((m1 >> k) & 1u);
            if (lane == 0) wc[wid][k] = (float)(__popcll(b0) + __popcll(b1));
        }
        __syncthreads();
        if (threadIdx.x < 16) {
            int k = threadIdx.x;
            float s = wc[0][k] + wc[1][k] + wc[2][k] + wc[3][k];
            atomicAdd(counts_s + k * 32 + (blockIdx.x & 31), s);
        }
    } else {
        int b2 = blockIdx.x - 512;
        int p = (b2 * 256 + threadIdx.x) * 2;
        float s0 = 0.f, s1 = 0.f;
        #pragma unroll 16
        for (int c = 0; c < CCH; ++c) {
            float2 v = *(const float2*)(x2 + (size_t)c * PIX + p);
            s0 = fmaf(v.x, v.x, s0);
            s1 = fmaf(v.y, v.y, s1);
        }
        float2 y;
        y.x = (s0 > 0.f) ? rsqrtf(s0) : 0.f;
        y.y = (s1 > 0.f) ? rsqrtf(s1) : 0.f;
        *(float2*)(yv + p) = y;
    }
}

__device__ __forceinline__ float wred64(float v) {
    #pragma unroll
    for (int o = 32; o > 0; o >>= 1) v += __shfl_xor(v, o, 64);
    return v;
}

// ---------------- K2: MFMA masked GEMMs, batched loads for MLP ---------------------
// blocks [0,2048):    A-pass: psum_c += M@X1^T, psumsq_c += M@(X1^2)^T  (128 px/blk)
// blocks [2048,4096): B-pass: G_c += M@(y*X2)^T
// A[m=lane&15][k=quad*8+j] (mask, 0/1 bf16 exact); B[k][n=lane&15] = x split hi/lo
// (truncation split, rel err <= 2^-16); D: col=lane&15(+16*wave), row=quad*4+reg.
// All 12-20 global loads issued before compute -> ~200-320 B in flight per lane.
__global__ __launch_bounds__(256) void k2_mfma(
        const float* __restrict__ x1, const float* __restrict__ x2,
        const unsigned short* __restrict__ packed, const float* __restrict__ yv,
        float* __restrict__ psum_c, float* __restrict__ psumsq_c,
        float* __restrict__ G_c) {
    int b = blockIdx.x;
    bool TB = (b >= 2048);
    if (TB) b -= 2048;
    int lane = threadIdx.x & 63;
    int wv   = threadIdx.x >> 6;
    int quad = lane >> 4;
    int n    = lane & 15;
    int ch   = wv * 16 + n;
    int base = b * 128;
    int cp   = b & 31;

    const float* Xrow = (TB ? x2 : x1) + (size_t)ch * PIX;

    int4 pk[4]; float4 xa[4], xb[4], ya[4], yb[4];
    #pragma unroll
    for (int i = 0; i < 4; ++i) {
        int kof = base + i * 32 + (quad << 3);
        pk[i] = *(const int4*)(packed + kof);
        xa[i] = *(const float4*)(Xrow + kof);
        xb[i] = *(const float4*)(Xrow + kof + 4);
    }
    if (TB) {
        #pragma unroll
        for (int i = 0; i < 4; ++i) {
            int kof = base + i * 32 + (quad << 3);
            ya[i] = *(const float4*)(yv + kof);
            yb[i] = *(const float4*)(yv + kof + 4);
        }
    }

    f32x4 acc0 = {0.f, 0.f, 0.f, 0.f};
    f32x4 acc1 = {0.f, 0.f, 0.f, 0.f};
    const short ONE = (short)0x3F80;   // bf16 1.0

    #pragma unroll
    for (int i = 0; i < 4; ++i) {
        short8 af;
        af[0] = ((pk[i].x >> n) & 1)        ? ONE : (short)0;
        af[1] = ((pk[i].x >> (n + 16)) & 1) ? ONE : (short)0;
        af[2] = ((pk[i].y >> n) & 1)        ? ONE : (short)0;
        af[3] = ((pk[i].y >> (n + 16)) & 1) ? ONE : (short)0;
        af[4] = ((pk[i].z >> n) & 1)        ? ONE : (short)0;
        af[5] = ((pk[i].z >> (n + 16)) & 1) ? ONE : (short)0;
        af[6] = ((pk[i].w >> n) & 1)        ? ONE : (short)0;
        af[7] = ((pk[i].w >> (n + 16)) & 1) ? ONE : (short)0;

        float xs[8] = {xa[i].x, xa[i].y, xa[i].z, xa[i].w,
                       xb[i].x, xb[i].y, xb[i].z, xb[i].w};
        if (TB) {
            float ys[8] = {ya[i].x, ya[i].y, ya[i].z, ya[i].w,
                           yb[i].x, yb[i].y, yb[i].z, yb[i].w};
            #pragma unroll
            for (int j = 0; j < 8; ++j) xs[j] *= ys[j];
        }

        short8 bh, bl;
        #pragma unroll
        for (int j = 0; j < 8; ++j) {
            unsigned u = __float_as_uint(xs[j]);
            bh[j] = (short)(u >> 16);
            float hi = __uint_as_float(u & 0xFFFF0000u);
            bl[j] = (short)(__float_as_uint(xs[j] - hi) >> 16);
        }
        acc0 = __builtin_amdgcn_mfma_f32_16x16x32_bf16(af, bh, acc0, 0, 0, 0);
        acc0 = __builtin_amdgcn_mfma_f32_16x16x32_bf16(af, bl, acc0, 0, 0, 0);

        if (!TB) {
            short8 qh, ql;
            #pragma unroll
            for (int j = 0; j < 8; ++j) {
                float sq = xs[j] * xs[j];
                unsigned u = __float_as_uint(sq);
                qh[j] = (short)(u >> 16);
                float hi = __uint_as_float(u & 0xFFFF0000u);
                ql[j] = (short)(__float_as_uint(sq - hi) >> 16);
            }
            acc1 = __builtin_amdgcn_mfma_f32_16x16x32_bf16(af, qh, acc1, 0, 0, 0);
            acc1 = __builtin_amdgcn_mfma_f32_16x16x32_bf16(af, ql, acc1, 0, 0, 0);
        }
    }

    int col = wv * 16 + n;
    #pragma unroll
    for (int r = 0; r < 4; ++r) {
        int idx = cp * 1024 + (quad * 4 + r) * 64 + col;
        if (TB) {
            atomicAdd(G_c + idx, acc0[r]);
        } else {
            atomicAdd(psum_c + idx, acc0[r]);
            atomicAdd(psumsq_c + idx, acc1[r]);
        }
    }
}

// ---------------- K3: reduce 32 copies + finalize (fully parallel, LDS only) -------
__global__ __launch_bounds__(256) void k3_finalize(
        const int* __restrict__ labels, const float* __restrict__ counts_s,
        const float* __restrict__ psum_c, const float* __restrict__ psumsq_c,
        const float* __restrict__ G_c, float* __restrict__ out) {
    __shared__ float meansS[16][65];
    __shared__ float Gs[16][65];
    __shared__ float cntS[16], rawcS[16], nmS[16], stdS[16], rowS[16];
    __shared__ float ssq2[16][17];
    __shared__ float ssqS[16];
    __shared__ int   labS[16];
    __shared__ float simS[16][17];
    __shared__ float bred[4][6];
    int t = threadIdx.x;

    if (t < 16) {
        float s = 0.f;
        #pragma unroll 8
        for (int j = 0; j < 32; ++j) s += counts_s[t * 32 + j];
        rawcS[t] = s;
        cntS[t]  = fmaxf(s, 1.f);
        labS[t]  = labels[t];
    }
    // ssq2[k][seg] = sum over 4 channels (seg*4..) and 32 copies of psumsq
    {
        int k = t >> 4, seg = t & 15;
        float s = 0.f;
        for (int cp = 0; cp < 32; ++cp) {
            const float4 v = *(const float4*)(psumsq_c + cp * 1024 + k * 64 + seg * 4);
            s += v.x + v.y + v.z + v.w;
        }
        ssq2[k][seg] = s;
    }
    __syncthreads();
    if (t < 16) {
        float s = 0.f;
        #pragma unroll
        for (int seg = 0; seg < 16; ++seg) s += ssq2[t][seg];
        ssqS[t] = s;
    }
    for (int i = t; i < 1024; i += 256) {
        int k = i >> 6, c = i & 63;
        float sp = 0.f, sg = 0.f;
        #pragma unroll 8
        for (int cp = 0; cp < 32; ++cp) {
            sp += psum_c[cp * 1024 + i];
            sg += G_c[cp * 1024 + i];
        }
        meansS[k][c] = sp / cntS[k];
        Gs[k][c] = sg;
    }
    __syncthreads();
    if (t < 16) {
        float s2 = 0.f, sm = 0.f;
        for (int c = 0; c < 64; ++c) {
            float m = meansS[t][c];
            s2 = fmaf(m, m, s2);
            sm += m;
        }
        nmS[t] = sqrtf(s2);
        float ne = rawcS[t] * 64.f;
        float ma = (sm * cntS[t]) / fmaxf(ne, 1.f);   // == sum_all / max(n_elem,1)
        float var = (ssqS[t] - ne * ma * ma) / fmaxf(ne - 1.f, 1.f);
        stdS[t] = sqrtf(fmaxf(var, 0.f));
    }
    __syncthreads();
    {
        int i = t >> 4, j = t & 15;
        float d = 0.f;
        #pragma unroll 16
        for (int c = 0; c < 64; ++c) d = fmaf(meansS[i][c], Gs[j][c], d);
        simS[i][j] = d / (fmaxf(nmS[i], 1e-30f) * cntS[j]);
    }
    __syncthreads();
    if (t < 16) {
        float s = 0.f;
        int li = labS[t];
        for (int j = 0; j < 16; ++j)
            if (j != t && labS[j] == li) s += simS[t][j];
        rowS[t] = s;
    }
    float s0 = 0.f, s1 = 0.f, s2 = 0.f, c0 = 0.f, c1 = 0.f, c2 = 0.f;
    {
        int i = t >> 4, j = t & 15;
        int li = labS[i], lj = labS[j];
        if (li != lj) {
            float sv = simS[i][j];
            bool gi0 = li >= 1 && li <= 8,  gj0 = lj >= 1 && lj <= 8;
            bool gi1 = li >= 3 && li <= 10, gj1 = lj >= 3 && lj <= 10;
            bool gi2 = (li >= 1 && li <= 2) || (li >= 9 && li <= 10);
            bool gj2 = (lj >= 1 && lj <= 2) || (lj >= 9 && lj <= 10);
            if (gi0 && gj0) { s0 = sv; c0 = 1.f; }
            if (gi1 && gj1) { s1 = sv; c1 = 1.f; }
            if (gi2 && gj2) { s2 = sv; c2 = 1.f; }
        }
    }
    s0 = wred64(s0); s1 = wred64(s1); s2 = wred64(s2);
    c0 = wred64(c0); c1 = wred64(c1); c2 = wred64(c2);
    {
        int wid = t >> 6, lane = t & 63;
        if (lane == 0) {
            bred[wid][0] = s0; bred[wid][1] = s1; bred[wid][2] = s2;
            bred[wid][3] = c0; bred[wid][4] = c1; bred[wid][5] = c2;
        }
    }
    __syncthreads();
    if (t < 11) {
        float cc = 0.f, inst = 0.f, csim = 0.f, cstd = 0.f;
        for (int k = 0; k < 16; ++k) {
            if (labS[k] == t) {
                cc += 1.f;
                inst += simS[k][k];
                csim += rowS[k];
                cstd += stdS[k];
            }
        }
        if (cc > 1.f) {
            inst /= fmaxf(cc, 1.f);
            csim /= fmaxf(cc * (cc - 1.f), 1.f);
            cstd /= cc;
        }
        out[t]      = inst;
        out[11 + t] = csim;
        out[25 + t] = cstd;
    }
    if (t == 0) {
        float S0 = bred[0][0] + bred[1][0] + bred[2][0] + bred[3][0];
        float S1 = bred[0][1] + bred[1][1] + bred[2][1] + bred[3][1];
        float S2 = bred[0][2] + bred[1][2] + bred[2][2] + bred[3][2];
        float C0 = bred[0][3] + bred[1][3] + bred[2][3] + bred[3][3];
        float C1 = bred[0][4] + bred[1][4] + bred[2][4] + bred[3][4];
        float C2 = bred[0][5] + bred[1][5] + bred[2][5] + bred[3][5];
        out[22] = (C0 > 1.f) ? (S0 / C0) : S0;
        out[23] = (C1 > 1.f) ? (S1 / C1) : S1;
        out[24] = (C2 > 1.f) ? (S2 / C2) : S2;
    }
}

extern "C" void kernel_launch(void* const* d_in, const int* in_sizes, int n_in,
                              void* d_out, int out_size, void* d_ws, size_t ws_size,
                              hipStream_t stream) {
    const float* x1     = (const float*)d_in[0];
    const float* x2     = (const float*)d_in[1];
    const int*   masks  = (const int*)d_in[2];
    const int*   labels = (const int*)d_in[3];
    float* out = (float*)d_out;

    char* ws = (char*)d_ws;
    unsigned short* packed = (unsigned short*)ws;                    // 512 KB
    float* yv       = (float*)(ws + (size_t)PIX * 2);                // 1 MB
    float* counts_s = (float*)(ws + (size_t)PIX * 6);                // 512 f
    float* psum_c   = counts_s + 512;                                // 32*1024 f
    float* psumsq_c = psum_c + 32 * 1024;                            // 32*1024 f
    float* G_c      = psumsq_c + 32 * 1024;                          // 32*1024 f

    hipMemsetAsync(counts_s, 0, (512 + 3 * 32 * 1024) * sizeof(float), stream);
    k1_fused<<<1024, 256, 0, stream>>>(masks, x2, packed, counts_s, yv);
    k2_mfma<<<4096, 256, 0, stream>>>(x1, x2, packed, yv, psum_c, psumsq_c, G_c);
    k3_finalize<<<1, 256, 0, stream>>>(labels, counts_s, psum_c, psumsq_c, G_c, out);
}